// Round 1
// baseline (233.771 us; speedup 1.0000x reference)
//
#include <hip/hip_runtime.h>
#include <hip/hip_bf16.h>

// Problem: B=4, S=4096, D=1024, H=64.
//   qs = LN(x@Wq), ks = LN(x@Wk), vs = x@Wv
//   out = softmax(qs ks^T / sqrt(64)) @ vs        (per batch)
// Strategy: bf16 MFMA (16x16x32) for all matmuls, fp32 accumulate.
//   k1: W -> bf16 transposed WT[192][1024]
//   k2: projection GEMM M=16384 N=192 K=1024 + fused LayerNorm (q pre-scaled
//       by 0.125) -> q_bf[16384][64], k_bf[16384][64], vT[B][64][4096]
//   k3: flash attention, 64 Q-rows/block (4 waves x 16 rows), KV tiles of 64.

typedef __bf16 bf16x8 __attribute__((ext_vector_type(8)));
typedef float f32x4 __attribute__((ext_vector_type(4)));

#define NROW 16384   // B*S
#define DD   1024
#define HH   64
#define SS   4096

static __device__ inline unsigned short f2bf_u(float x) {
    __bf16 b = (__bf16)x;
    return __builtin_bit_cast(unsigned short, b);
}

// ---------------------------------------------------------------- kernel 1
// WT[mat*64 + h][k] = (bf16) W_mat[k][h]
__global__ __launch_bounds__(256) void k_transpose_w(
    const float* __restrict__ Wq, const float* __restrict__ Wk,
    const float* __restrict__ Wv, __bf16* __restrict__ WT) {
  int idx = blockIdx.x * 256 + threadIdx.x;   // 0..196607
  int mat = idx >> 16;
  int rem = idx & 65535;                      // k*64 + h (coalesced read)
  int k = rem >> 6, h = rem & 63;
  const float* W = (mat == 0) ? Wq : ((mat == 1) ? Wk : Wv);
  WT[(size_t)(mat * 64 + h) * 1024 + k] = (__bf16)W[rem];
}

// ---------------------------------------------------------------- kernel 2
// One block: 64 rows x 192 cols. 4 waves, wave w owns rows 16w..16w+15.
// K loop in steps of 32. LDS padded to stride 40 (2-way bank alias = free).
__global__ __launch_bounds__(256) void k_proj(
    const float* __restrict__ X, const __bf16* __restrict__ WT,
    __bf16* __restrict__ qb, __bf16* __restrict__ kbp, __bf16* __restrict__ vT) {
  __shared__ __bf16 Xs[64 * 40];
  __shared__ __bf16 Ws[192 * 40];
  const int t = threadIdx.x;
  const int lane = t & 63, w = t >> 6;
  const int quad = lane >> 4, m = lane & 15;
  const int Mb = blockIdx.x * 64;

  f32x4 acc[12];
#pragma unroll
  for (int i = 0; i < 12; i++) acc[i] = (f32x4){0.f, 0.f, 0.f, 0.f};

  for (int ko = 0; ko < DD; ko += 32) {
    {   // stage X tile: 64 rows x 32 k, fp32 -> bf16
      int row = t >> 2, k0 = (t & 3) * 8;
      const float4* src =
          reinterpret_cast<const float4*>(&X[(size_t)(Mb + row) * DD + ko + k0]);
      float4 a = src[0], b = src[1];
      __bf16* dst = &Xs[row * 40 + k0];
      dst[0] = (__bf16)a.x; dst[1] = (__bf16)a.y;
      dst[2] = (__bf16)a.z; dst[3] = (__bf16)a.w;
      dst[4] = (__bf16)b.x; dst[5] = (__bf16)b.y;
      dst[6] = (__bf16)b.z; dst[7] = (__bf16)b.w;
    }
#pragma unroll
    for (int i = 0; i < 3; i++) {   // stage W^T tile: 192 rows x 32 k
      int c = t + i * 256;          // chunk of 8 elems; c < 768
      int row = c >> 2, k0 = (c & 3) * 8;
      *reinterpret_cast<bf16x8*>(&Ws[row * 40 + k0]) =
          *reinterpret_cast<const bf16x8*>(&WT[(size_t)row * DD + ko + k0]);
    }
    __syncthreads();
    bf16x8 a = *reinterpret_cast<const bf16x8*>(&Xs[(m + 16 * w) * 40 + quad * 8]);
#pragma unroll
    for (int nt = 0; nt < 12; nt++) {
      bf16x8 bfr =
          *reinterpret_cast<const bf16x8*>(&Ws[(m + 16 * nt) * 40 + quad * 8]);
      acc[nt] = __builtin_amdgcn_mfma_f32_16x16x32_bf16(a, bfr, acc[nt], 0, 0, 0);
    }
    __syncthreads();
  }

  // ---- fused LayerNorm over H=64 for q (mat 0) and k (mat 1).
  // Row r = quad*4+reg; its 64 values sit in 16 lanes (fixed quad) x 4 frags.
#pragma unroll
  for (int mat = 0; mat < 2; mat++) {
#pragma unroll
    for (int reg = 0; reg < 4; reg++) {
      float s = 0.f, s2 = 0.f;
#pragma unroll
      for (int ntl = 0; ntl < 4; ntl++) {
        float x = acc[mat * 4 + ntl][reg];
        s += x; s2 += x * x;
      }
#pragma unroll
      for (int off = 1; off < 16; off <<= 1) {
        s += __shfl_xor(s, off, 64);
        s2 += __shfl_xor(s2, off, 64);
      }
      float mu = s * (1.0f / 64.0f);
      float var = s2 * (1.0f / 64.0f) - mu * mu;
      float rstd = rsqrtf(var + 1e-5f);
      float scl = (mat == 0) ? 0.125f * rstd : rstd;  // fold 1/sqrt(H) into q
#pragma unroll
      for (int ntl = 0; ntl < 4; ntl++)
        acc[mat * 4 + ntl][reg] = (acc[mat * 4 + ntl][reg] - mu) * scl;
    }
  }

  const int rowbase = Mb + 16 * w + quad * 4;
#pragma unroll
  for (int nt = 0; nt < 4; nt++) {
#pragma unroll
    for (int reg = 0; reg < 4; reg++) {
      qb[(size_t)(rowbase + reg) * HH + m + 16 * nt] = (__bf16)acc[nt][reg];
      kbp[(size_t)(rowbase + reg) * HH + m + 16 * nt] = (__bf16)acc[4 + nt][reg];
    }
  }
  // v stored transposed: vT[b][h][s]; the 4 regs are 4 consecutive s -> 8B store
  const int b = Mb >> 12;
  const int s0 = (Mb & 4095) + 16 * w + quad * 4;
#pragma unroll
  for (int nt = 0; nt < 4; nt++) {
    ushort4 pk = make_ushort4(f2bf_u(acc[8 + nt][0]), f2bf_u(acc[8 + nt][1]),
                              f2bf_u(acc[8 + nt][2]), f2bf_u(acc[8 + nt][3]));
    *reinterpret_cast<ushort4*>(
        &vT[((size_t)(b * 64) + m + 16 * nt) * SS + s0]) = pk;
  }
}

// ---------------------------------------------------------------- kernel 3
// Flash attention. Block: 64 Q-rows (wave w -> rows 16w..16w+15), KV tile 64.
// LDS stride 72 everywhere -> only 2-way bank aliasing (free on CDNA4).
__global__ __launch_bounds__(256) void k_attn(
    const __bf16* __restrict__ qb, const __bf16* __restrict__ kbp,
    const __bf16* __restrict__ vT, float* __restrict__ out) {
  __shared__ __bf16 Klds[64 * 72];
  __shared__ __bf16 Vlds[64 * 72];       // transposed: [h][key]
  __shared__ __bf16 Plds[4 * 16 * 72];   // per-wave P tile [16 qrow][64 key]
  const int t = threadIdx.x, lane = t & 63, w = t >> 6;
  const int quad = lane >> 4, m = lane & 15;
  const int Mb = blockIdx.x * 64;
  const int b = Mb >> 12;
  const size_t kvbase = (size_t)b * SS * HH;

  // Q A-fragments held in registers for the whole KV loop (q pre-scaled)
  bf16x8 qf[2];
  {
    const int row = Mb + 16 * w + m;
    qf[0] = *reinterpret_cast<const bf16x8*>(&qb[(size_t)row * HH + quad * 8]);
    qf[1] = *reinterpret_cast<const bf16x8*>(&qb[(size_t)row * HH + 32 + quad * 8]);
  }
  float mrow[4] = {-1e30f, -1e30f, -1e30f, -1e30f};
  float lrow[4] = {0.f, 0.f, 0.f, 0.f};
  f32x4 O[4];
#pragma unroll
  for (int i = 0; i < 4; i++) O[i] = (f32x4){0.f, 0.f, 0.f, 0.f};

  for (int kb0 = 0; kb0 < SS; kb0 += 64) {
#pragma unroll
    for (int i = 0; i < 2; i++) {   // stage K (row=key) and V^T (row=h)
      int c = t + i * 256;          // 512 chunks x 8 elems
      int row = c >> 3, k0 = (c & 7) * 8;
      *reinterpret_cast<bf16x8*>(&Klds[row * 72 + k0]) =
          *reinterpret_cast<const bf16x8*>(
              &kbp[kvbase + (size_t)(kb0 + row) * HH + k0]);
      *reinterpret_cast<bf16x8*>(&Vlds[row * 72 + k0]) =
          *reinterpret_cast<const bf16x8*>(
              &vT[(size_t)(b * 64 + row) * SS + kb0 + k0]);
    }
    __syncthreads();

    // S = Q K^T  (scores already scaled by 1/8 via q)
    f32x4 sc[4];
#pragma unroll
    for (int nt = 0; nt < 4; nt++) sc[nt] = (f32x4){0.f, 0.f, 0.f, 0.f};
#pragma unroll
    for (int kk = 0; kk < 2; kk++) {
#pragma unroll
      for (int nt = 0; nt < 4; nt++) {
        bf16x8 bf = *reinterpret_cast<const bf16x8*>(
            &Klds[(m + 16 * nt) * 72 + 32 * kk + quad * 8]);
        sc[nt] = __builtin_amdgcn_mfma_f32_16x16x32_bf16(qf[kk], bf, sc[nt], 0, 0, 0);
      }
    }

    // online softmax; row r = quad*4+reg lives in 16 lanes (shfl over 1,2,4,8)
#pragma unroll
    for (int reg = 0; reg < 4; reg++) {
      float tm = fmaxf(fmaxf(sc[0][reg], sc[1][reg]),
                       fmaxf(sc[2][reg], sc[3][reg]));
#pragma unroll
      for (int off = 1; off < 16; off <<= 1)
        tm = fmaxf(tm, __shfl_xor(tm, off, 64));
      float mn = fmaxf(mrow[reg], tm);
      float alpha = __expf(mrow[reg] - mn);
      mrow[reg] = mn;
      float ps = 0.f;
#pragma unroll
      for (int nt = 0; nt < 4; nt++) {
        float p = __expf(sc[nt][reg] - mn);
        sc[nt][reg] = p;
        ps += p;
      }
#pragma unroll
      for (int off = 1; off < 16; off <<= 1) ps += __shfl_xor(ps, off, 64);
      lrow[reg] = lrow[reg] * alpha + ps;
#pragma unroll
      for (int ht = 0; ht < 4; ht++) O[ht][reg] *= alpha;
    }

    // P (C-layout) -> LDS -> A-layout for PV
    __bf16* Pw = &Plds[w * 16 * 72];
#pragma unroll
    for (int nt = 0; nt < 4; nt++)
#pragma unroll
      for (int reg = 0; reg < 4; reg++)
        Pw[(quad * 4 + reg) * 72 + m + 16 * nt] = (__bf16)sc[nt][reg];

#pragma unroll
    for (int kk = 0; kk < 2; kk++) {
      bf16x8 pf =
          *reinterpret_cast<const bf16x8*>(&Pw[m * 72 + 32 * kk + quad * 8]);
#pragma unroll
      for (int ht = 0; ht < 4; ht++) {
        bf16x8 vf = *reinterpret_cast<const bf16x8*>(
            &Vlds[(m + 16 * ht) * 72 + 32 * kk + quad * 8]);
        O[ht] = __builtin_amdgcn_mfma_f32_16x16x32_bf16(pf, vf, O[ht], 0, 0, 0);
      }
    }
    __syncthreads();
  }

  const int rowbase = Mb + 16 * w + quad * 4;
#pragma unroll
  for (int ht = 0; ht < 4; ht++)
#pragma unroll
    for (int reg = 0; reg < 4; reg++)
      out[(size_t)(rowbase + reg) * HH + m + 16 * ht] = O[ht][reg] / lrow[reg];
}

// ---------------------------------------------------------------- launch
extern "C" void kernel_launch(void* const* d_in, const int* in_sizes, int n_in,
                              void* d_out, int out_size, void* d_ws, size_t ws_size,
                              hipStream_t stream) {
  const float* X  = (const float*)d_in[0];
  const float* Wq = (const float*)d_in[1];
  const float* Wk = (const float*)d_in[2];
  const float* Wv = (const float*)d_in[3];
  float* out = (float*)d_out;
  char* ws = (char*)d_ws;

  __bf16* WT  = (__bf16*)(ws);                              // 384 KB
  __bf16* qb  = (__bf16*)(ws + 512 * 1024);                 // 2 MB
  __bf16* kbp = (__bf16*)(ws + 512 * 1024 + 2 * 1024 * 1024);
  __bf16* vT  = (__bf16*)(ws + 512 * 1024 + 4 * 1024 * 1024);

  hipLaunchKernelGGL(k_transpose_w, dim3(768), dim3(256), 0, stream, Wq, Wk, Wv, WT);
  hipLaunchKernelGGL(k_proj, dim3(NROW / 64), dim3(256), 0, stream, X, WT, qb, kbp, vT);
  hipLaunchKernelGGL(k_attn, dim3(NROW / 64), dim3(256), 0, stream, qb, kbp, vT, out);
}

// Round 2
// 172.985 us; speedup vs baseline: 1.3514x; 1.3514x over previous
//
#include <hip/hip_runtime.h>
#include <hip/hip_bf16.h>

// B=4, S=4096, D=1024, H=64.
// qs = LN(x@Wq), ks = LN(x@Wk), vs = x@Wv; out = softmax(qs ks^T/8) @ vs.
// Key facts exploited:
//  - LN rows have exactly ||r||=8, so |score| <= 8 -> NO online softmax needed
//    (exp safe in fp32). l computed via ones-MFMA, combined by plain sums.
//  - KV split 4-way for occupancy (1 block/CU -> 4), partials in ws + combine.
//  - LDS stride 68 elems (34 dw == 2 mod 32 -> 2-way bank alias = free), all
//    fragment loads as ds_read_b64 pairs (rows only 8B-aligned).

typedef __bf16 bf16x8 __attribute__((ext_vector_type(8)));
typedef __bf16 bf16x4 __attribute__((ext_vector_type(4)));
typedef float f32x4 __attribute__((ext_vector_type(4)));

#define NROW 16384
#define DD   1024
#define HH   64
#define SS   4096
#define LS   68      // LDS row stride (elements)

static __device__ inline unsigned short f2bf_u(float x) {
  __bf16 b = (__bf16)x;
  return __builtin_bit_cast(unsigned short, b);
}
static __device__ inline uint2 pk4(float a, float b, float c, float d) {
  return make_uint2((unsigned)f2bf_u(a) | ((unsigned)f2bf_u(b) << 16),
                    (unsigned)f2bf_u(c) | ((unsigned)f2bf_u(d) << 16));
}
// 8 bf16 from an 8B-aligned LDS address: two ds_read_b64
static __device__ inline bf16x8 ld8(const __bf16* p) {
  bf16x4 lo = *reinterpret_cast<const bf16x4*>(p);
  bf16x4 hi = *reinterpret_cast<const bf16x4*>(p + 4);
  return __builtin_shufflevector(lo, hi, 0, 1, 2, 3, 4, 5, 6, 7);
}

// ---------------------------------------------------------------- kernel 1
__global__ __launch_bounds__(256) void k_transpose_w(
    const float* __restrict__ Wq, const float* __restrict__ Wk,
    const float* __restrict__ Wv, __bf16* __restrict__ WT) {
  int idx = blockIdx.x * 256 + threadIdx.x;   // 0..196607
  int mat = idx >> 16;
  int rem = idx & 65535;                      // k*64 + h (coalesced read)
  int k = rem >> 6, h = rem & 63;
  const float* W = (mat == 0) ? Wq : ((mat == 1) ? Wk : Wv);
  WT[(size_t)(mat * 64 + h) * DD + k] = (__bf16)W[rem];
}

// ---------------------------------------------------------------- kernel 2
// 32 rows x 192 cols per block, 2 waves (wave w -> rows 16w..16w+15).
// Register double-buffer prefetch of next K-step's X and W tiles.
__global__ __launch_bounds__(128, 2) void k_proj(
    const float* __restrict__ X, const __bf16* __restrict__ WT,
    __bf16* __restrict__ qb, __bf16* __restrict__ kbp, __bf16* __restrict__ vT) {
  __shared__ __bf16 Xs[32 * LS];
  __shared__ __bf16 Ws[192 * LS];
  const int t = threadIdx.x;
  const int lane = t & 63, w = t >> 6;
  const int quad = lane >> 4, m = lane & 15;
  const int Mb = blockIdx.x * 32;

  const int xrow = t >> 2, xk0 = (t & 3) * 8;

  f32x4 acc[12];
#pragma unroll
  for (int i = 0; i < 12; i++) acc[i] = (f32x4){0.f, 0.f, 0.f, 0.f};

  float4 xa, xb;
  bf16x8 wch[6];
  xa = *reinterpret_cast<const float4*>(&X[(size_t)(Mb + xrow) * DD + xk0]);
  xb = *reinterpret_cast<const float4*>(&X[(size_t)(Mb + xrow) * DD + xk0 + 4]);
#pragma unroll
  for (int i = 0; i < 6; i++) {
    int c = t + i * 128, wr = c >> 2, wk = (c & 3) * 8;
    wch[i] = *reinterpret_cast<const bf16x8*>(&WT[(size_t)wr * DD + wk]);
  }

  for (int ko = 0; ko < DD; ko += 32) {
    __syncthreads();                      // prev compute done; LDS writable
    {
      __bf16* xd = &Xs[xrow * LS + xk0];
      *reinterpret_cast<uint2*>(xd) = pk4(xa.x, xa.y, xa.z, xa.w);
      *reinterpret_cast<uint2*>(xd + 4) = pk4(xb.x, xb.y, xb.z, xb.w);
#pragma unroll
      for (int i = 0; i < 6; i++) {
        int c = t + i * 128, wr = c >> 2, wk = (c & 3) * 8;
        __bf16* wd = &Ws[wr * LS + wk];
        uint4 raw = __builtin_bit_cast(uint4, wch[i]);
        *reinterpret_cast<uint2*>(wd) = make_uint2(raw.x, raw.y);
        *reinterpret_cast<uint2*>(wd + 4) = make_uint2(raw.z, raw.w);
      }
    }
    __syncthreads();                      // LDS ready
    if (ko + 32 < DD) {                   // prefetch next tile (in flight)
      xa = *reinterpret_cast<const float4*>(
          &X[(size_t)(Mb + xrow) * DD + ko + 32 + xk0]);
      xb = *reinterpret_cast<const float4*>(
          &X[(size_t)(Mb + xrow) * DD + ko + 32 + xk0 + 4]);
#pragma unroll
      for (int i = 0; i < 6; i++) {
        int c = t + i * 128, wr = c >> 2, wk = (c & 3) * 8;
        wch[i] = *reinterpret_cast<const bf16x8*>(
            &WT[(size_t)wr * DD + ko + 32 + wk]);
      }
    }
    bf16x8 a = ld8(&Xs[(m + 16 * w) * LS + quad * 8]);
#pragma unroll
    for (int nt = 0; nt < 12; nt++) {
      bf16x8 bfr = ld8(&Ws[(m + 16 * nt) * LS + quad * 8]);
      acc[nt] = __builtin_amdgcn_mfma_f32_16x16x32_bf16(a, bfr, acc[nt], 0, 0, 0);
    }
  }

  // fused LayerNorm over H=64 for q (mat 0) and k (mat 1)
#pragma unroll
  for (int mat = 0; mat < 2; mat++) {
#pragma unroll
    for (int reg = 0; reg < 4; reg++) {
      float s = 0.f, s2 = 0.f;
#pragma unroll
      for (int ntl = 0; ntl < 4; ntl++) {
        float x = acc[mat * 4 + ntl][reg];
        s += x; s2 += x * x;
      }
#pragma unroll
      for (int off = 1; off < 16; off <<= 1) {
        s += __shfl_xor(s, off, 64);
        s2 += __shfl_xor(s2, off, 64);
      }
      float mu = s * (1.0f / 64.0f);
      float var = s2 * (1.0f / 64.0f) - mu * mu;
      float rstd = rsqrtf(var + 1e-5f);
      float scl = (mat == 0) ? 0.125f * rstd : rstd;  // fold 1/sqrt(H) into q
#pragma unroll
      for (int ntl = 0; ntl < 4; ntl++)
        acc[mat * 4 + ntl][reg] = (acc[mat * 4 + ntl][reg] - mu) * scl;
    }
  }

  const int rowbase = Mb + 16 * w + quad * 4;
#pragma unroll
  for (int nt = 0; nt < 4; nt++)
#pragma unroll
    for (int reg = 0; reg < 4; reg++) {
      qb[(size_t)(rowbase + reg) * HH + m + 16 * nt] = (__bf16)acc[nt][reg];
      kbp[(size_t)(rowbase + reg) * HH + m + 16 * nt] = (__bf16)acc[4 + nt][reg];
    }
  const int b = Mb >> 12;
  const int s0 = (Mb & 4095) + 16 * w + quad * 4;
#pragma unroll
  for (int nt = 0; nt < 4; nt++) {
    ushort4 pk = make_ushort4(f2bf_u(acc[8 + nt][0]), f2bf_u(acc[8 + nt][1]),
                              f2bf_u(acc[8 + nt][2]), f2bf_u(acc[8 + nt][3]));
    *reinterpret_cast<ushort4*>(
        &vT[((size_t)(b * 64) + m + 16 * nt) * SS + s0]) = pk;
  }
}

// ---------------------------------------------------------------- kernel 3
// Attention partial: block = (q-tile of 64 rows) x (KV split of 1024 keys).
// No online softmax (|score|<=8). O computed transposed (A=V^T, B=P) so each
// lane owns one q-row; l via ones-MFMA. Partials stored fp32 (permuted cols).
__global__ __launch_bounds__(256, 4) void k_attn(
    const __bf16* __restrict__ qb, const __bf16* __restrict__ kbp,
    const __bf16* __restrict__ vT, float* __restrict__ Op,
    float* __restrict__ lp) {
  __shared__ __bf16 Klds[64 * LS];      // [key][h]
  __shared__ __bf16 Vlds[64 * LS];      // [h][key]
  __shared__ __bf16 Plds[4][16 * LS];   // per-wave [q][key]
  const int t = threadIdx.x, lane = t & 63, w = t >> 6;
  const int quad = lane >> 4, m = lane & 15;
  const int qt = blockIdx.x >> 2, sp = blockIdx.x & 3;
  const int Mb = qt * 64;
  const int b = Mb >> 12;
  const size_t kvbase = (size_t)b * SS * HH;

  bf16x8 qf[2];
  {
    const int row = Mb + 16 * w + m;
    qf[0] = *reinterpret_cast<const bf16x8*>(&qb[(size_t)row * HH + quad * 8]);
    qf[1] = *reinterpret_cast<const bf16x8*>(&qb[(size_t)row * HH + 32 + quad * 8]);
  }
  bf16x8 ones;
#pragma unroll
  for (int i = 0; i < 8; i++) ones[i] = (__bf16)1.0f;

  f32x4 O[4], lac;
#pragma unroll
  for (int i = 0; i < 4; i++) O[i] = (f32x4){0.f, 0.f, 0.f, 0.f};
  lac = (f32x4){0.f, 0.f, 0.f, 0.f};

  for (int kb0 = sp * (SS / 4); kb0 < (sp + 1) * (SS / 4); kb0 += 64) {
#pragma unroll
    for (int i = 0; i < 2; i++) {     // stage K and V^T tiles
      int c = t + i * 256;
      int row = c >> 3, k0 = (c & 7) * 8;
      uint4 kd = *reinterpret_cast<const uint4*>(
          &kbp[kvbase + (size_t)(kb0 + row) * HH + k0]);
      uint4 vd = *reinterpret_cast<const uint4*>(
          &vT[(size_t)(b * 64 + row) * SS + kb0 + k0]);
      __bf16* kp = &Klds[row * LS + k0];
      __bf16* vp = &Vlds[row * LS + k0];
      *reinterpret_cast<uint2*>(kp) = make_uint2(kd.x, kd.y);
      *reinterpret_cast<uint2*>(kp + 4) = make_uint2(kd.z, kd.w);
      *reinterpret_cast<uint2*>(vp) = make_uint2(vd.x, vd.y);
      *reinterpret_cast<uint2*>(vp + 4) = make_uint2(vd.z, vd.w);
    }
    __syncthreads();

    f32x4 sc[4];
#pragma unroll
    for (int nt = 0; nt < 4; nt++) sc[nt] = (f32x4){0.f, 0.f, 0.f, 0.f};
#pragma unroll
    for (int kk = 0; kk < 2; kk++)
#pragma unroll
      for (int nt = 0; nt < 4; nt++) {
        bf16x8 bf = ld8(&Klds[(m + 16 * nt) * LS + 32 * kk + quad * 8]);
        sc[nt] = __builtin_amdgcn_mfma_f32_16x16x32_bf16(qf[kk], bf, sc[nt], 0, 0, 0);
      }

    __bf16* Pw = Plds[w];
#pragma unroll
    for (int nt = 0; nt < 4; nt++)
#pragma unroll
      for (int reg = 0; reg < 4; reg++)
        Pw[(quad * 4 + reg) * LS + m + 16 * nt] = (__bf16)__expf(sc[nt][reg]);

#pragma unroll
    for (int kk = 0; kk < 2; kk++) {
      bf16x8 pf = ld8(&Pw[m * LS + 32 * kk + quad * 8]);
      lac = __builtin_amdgcn_mfma_f32_16x16x32_bf16(ones, pf, lac, 0, 0, 0);
#pragma unroll
      for (int ht = 0; ht < 4; ht++) {
        bf16x8 vf = ld8(&Vlds[(m + 16 * ht) * LS + 32 * kk + quad * 8]);
        O[ht] = __builtin_amdgcn_mfma_f32_16x16x32_bf16(vf, pf, O[ht], 0, 0, 0);
      }
    }
    __syncthreads();
  }

  // lane owns q-row m: O[ht][reg] = out^T[h=16ht+4quad+reg][row].
  // Store permuted (quad*16 + ht*4 + reg) -> contiguous 64B per lane.
  const int rowg = Mb + 16 * w + m;
  float4* obase = reinterpret_cast<float4*>(
      &Op[((size_t)sp * NROW + rowg) * HH + quad * 16]);
#pragma unroll
  for (int ht = 0; ht < 4; ht++)
    obase[ht] = make_float4(O[ht][0], O[ht][1], O[ht][2], O[ht][3]);
  if (quad == 0) lp[sp * NROW + rowg] = lac[0];
}

// ---------------------------------------------------------------- kernel 4
__global__ __launch_bounds__(256) void k_comb(const float* __restrict__ Op,
                                              const float* __restrict__ lp,
                                              float* __restrict__ out) {
  int idx = blockIdx.x * 256 + threadIdx.x;   // < NROW*HH
  int row = idx >> 6, h = idx & 63;
  int soff = ((h >> 2) & 3) * 16 + (h >> 4) * 4 + (h & 3);
  size_t sbase = (size_t)row * HH + soff;
  float o = 0.f, l = 0.f;
#pragma unroll
  for (int j = 0; j < 4; j++) {
    o += Op[(size_t)j * NROW * HH + sbase];
    l += lp[j * NROW + row];
  }
  out[idx] = o / l;
}

// ---------------------------------------------------------------- launch
extern "C" void kernel_launch(void* const* d_in, const int* in_sizes, int n_in,
                              void* d_out, int out_size, void* d_ws, size_t ws_size,
                              hipStream_t stream) {
  const float* X  = (const float*)d_in[0];
  const float* Wq = (const float*)d_in[1];
  const float* Wk = (const float*)d_in[2];
  const float* Wv = (const float*)d_in[3];
  float* out = (float*)d_out;
  char* ws = (char*)d_ws;

  __bf16* WT  = (__bf16*)(ws);                          // 384 KB
  __bf16* qb  = (__bf16*)(ws + (size_t)512 * 1024);     // 2 MB
  __bf16* kbp = (__bf16*)(ws + (size_t)2560 * 1024);    // 2 MB
  __bf16* vT  = (__bf16*)(ws + (size_t)4608 * 1024);    // 2 MB
  float*  Op  = (float*)(ws + (size_t)6656 * 1024);     // 16 MB (4 splits)
  float*  lp  = (float*)(ws + (size_t)23040 * 1024);    // 256 KB

  hipLaunchKernelGGL(k_transpose_w, dim3(768), dim3(256), 0, stream, Wq, Wk, Wv, WT);
  hipLaunchKernelGGL(k_proj, dim3(NROW / 32), dim3(128), 0, stream, X, WT, qb, kbp, vT);
  hipLaunchKernelGGL(k_attn, dim3((NROW / 64) * 4), dim3(256), 0, stream, qb, kbp, vT, Op, lp);
  hipLaunchKernelGGL(k_comb, dim3(NROW * HH / 256), dim3(256), 0, stream, Op, lp, out);
}